// Round 2
// baseline (332.195 us; speedup 1.0000x reference)
//
#include <hip/hip_runtime.h>
#include <hip/hip_bf16.h>

// SlotAttention on MI355X. B=64, N=4096, Din=D=64, S=7, H=128, 3 iters.
// v2: proj = register-direct MFMA (no LDS, no barriers); attn = reg-k +
// vectorized LDS, intra-wave chunk flow (no per-chunk barriers); small
// kernels parallelized; post kernel fuses GRU+MLP+LN+q-for-next-iter.

#define NB 64
#define NN 4096
#define NS 7
#define LN_EPS 1e-3f
#define EPS_ATTN 1e-8f

typedef __attribute__((ext_vector_type(8))) __bf16 bf16x8;
typedef __attribute__((ext_vector_type(8))) unsigned short u16x8;
typedef __attribute__((ext_vector_type(4))) float f32x4;

__device__ __forceinline__ unsigned short f2bf(float f) {
    unsigned int x = __float_as_uint(f);
    x += 0x7FFFu + ((x >> 16) & 1u);
    return (unsigned short)(x >> 16);
}

__device__ __forceinline__ void unpack8(uint4 u, float* f) {
    f[0] = __uint_as_float(u.x << 16); f[1] = __uint_as_float(u.x & 0xFFFF0000u);
    f[2] = __uint_as_float(u.y << 16); f[3] = __uint_as_float(u.y & 0xFFFF0000u);
    f[4] = __uint_as_float(u.z << 16); f[5] = __uint_as_float(u.z & 0xFFFF0000u);
    f[6] = __uint_as_float(u.w << 16); f[7] = __uint_as_float(u.w & 0xFFFF0000u);
}

// ---------------- prep: G^T = (g (.) W)^T bf16, colsums ----------------
__global__ __launch_bounds__(64) void prep_kernel(
        const float* __restrict__ Wk, const float* __restrict__ Wv,
        const float* __restrict__ g, const float* __restrict__ bb,
        unsigned short* __restrict__ GkT, unsigned short* __restrict__ GvT,
        float* __restrict__ cgk, float* __restrict__ cbk,
        float* __restrict__ cgv, float* __restrict__ cbv) {
    int j = blockIdx.x & 63, mat = blockIdx.x >> 6, d = threadIdx.x;
    const float* W = mat ? Wv : Wk;
    unsigned short* GT = mat ? GvT : GkT;
    float* cg = mat ? cgv : cgk;
    float* cb = mat ? cbv : cbk;
    float w = W[d * 64 + j];
    float gv = g[d], bv = bb[d];
    GT[j * 64 + d] = f2bf(gv * w);
    float sg = gv * w, sb = bv * w;
#pragma unroll
    for (int off = 1; off < 64; off <<= 1) {
        sg += __shfl_xor(sg, off);
        sb += __shfl_xor(sb, off);
    }
    if (d == 0) { cg[j] = sg; cb[j] = sb; }
}

// ---------------- init slots ----------------
__global__ void init_slots_kernel(const float* __restrict__ noise, const float* __restrict__ mu,
                                  const float* __restrict__ lsig, float* __restrict__ slots) {
    int idx = blockIdx.x * 256 + threadIdx.x;
    if (idx < NB * NS * 64) {
        int d = idx & 63;
        slots[idx] = mu[d] + __expf(lsig[d]) * noise[idx];
    }
}

// ---------------- proj: k,v = LN(x)@W via MFMA, register-direct ----------------
__global__ __launch_bounds__(256) void proj_kernel(
        const float* __restrict__ x, const unsigned short* __restrict__ GkT,
        const unsigned short* __restrict__ GvT,
        const float* __restrict__ cgk, const float* __restrict__ cbk,
        const float* __restrict__ cgv, const float* __restrict__ cbv,
        unsigned short* __restrict__ kout, unsigned short* __restrict__ vout) {
    int t = threadIdx.x;
    int w = t >> 6, lane = t & 63;
    int h = lane >> 4, rloc = lane & 15;
    long brow = (long)blockIdx.x * 64 + w * 16;
    const float* xr = x + (brow + rloc) * 64 + h * 8;
    float4 xa0 = *(const float4*)(xr);
    float4 xa1 = *(const float4*)(xr + 4);
    float4 xb0 = *(const float4*)(xr + 32);
    float4 xb1 = *(const float4*)(xr + 36);
    // row stats: this lane holds 16 of row (brow+rloc)'s 64 elems
    float s1 = xa0.x + xa0.y + xa0.z + xa0.w + xa1.x + xa1.y + xa1.z + xa1.w
             + xb0.x + xb0.y + xb0.z + xb0.w + xb1.x + xb1.y + xb1.z + xb1.w;
    float s2 = xa0.x*xa0.x + xa0.y*xa0.y + xa0.z*xa0.z + xa0.w*xa0.w
             + xa1.x*xa1.x + xa1.y*xa1.y + xa1.z*xa1.z + xa1.w*xa1.w
             + xb0.x*xb0.x + xb0.y*xb0.y + xb0.z*xb0.z + xb0.w*xb0.w
             + xb1.x*xb1.x + xb1.y*xb1.y + xb1.z*xb1.z + xb1.w*xb1.w;
    s1 += __shfl_xor(s1, 16); s2 += __shfl_xor(s2, 16);
    s1 += __shfl_xor(s1, 32); s2 += __shfl_xor(s2, 32);
    float m = s1 * (1.f / 64.f);
    float var = s2 * (1.f / 64.f) - m * m;
    float inv = rsqrtf(var + LN_EPS);
    // pack A fragments
    u16x8 pa0, pa1;
    pa0[0]=f2bf(xa0.x); pa0[1]=f2bf(xa0.y); pa0[2]=f2bf(xa0.z); pa0[3]=f2bf(xa0.w);
    pa0[4]=f2bf(xa1.x); pa0[5]=f2bf(xa1.y); pa0[6]=f2bf(xa1.z); pa0[7]=f2bf(xa1.w);
    pa1[0]=f2bf(xb0.x); pa1[1]=f2bf(xb0.y); pa1[2]=f2bf(xb0.z); pa1[3]=f2bf(xb0.w);
    pa1[4]=f2bf(xb1.x); pa1[5]=f2bf(xb1.y); pa1[6]=f2bf(xb1.z); pa1[7]=f2bf(xb1.w);
    bf16x8 a0 = __builtin_bit_cast(bf16x8, pa0);
    bf16x8 a1 = __builtin_bit_cast(bf16x8, pa1);
    f32x4 acck[4], accv[4];
#pragma unroll
    for (int nt = 0; nt < 4; ++nt) {
        acck[nt] = (f32x4){0.f, 0.f, 0.f, 0.f};
        accv[nt] = (f32x4){0.f, 0.f, 0.f, 0.f};
    }
#pragma unroll
    for (int nt = 0; nt < 4; ++nt) {
        const unsigned short* gk = GkT + (nt * 16 + rloc) * 64 + h * 8;
        const unsigned short* gv = GvT + (nt * 16 + rloc) * 64 + h * 8;
        bf16x8 bk0 = *(const bf16x8*)(gk);
        bf16x8 bk1 = *(const bf16x8*)(gk + 32);
        bf16x8 bv0 = *(const bf16x8*)(gv);
        bf16x8 bv1 = *(const bf16x8*)(gv + 32);
        acck[nt] = __builtin_amdgcn_mfma_f32_16x16x32_bf16(a0, bk0, acck[nt], 0, 0, 0);
        acck[nt] = __builtin_amdgcn_mfma_f32_16x16x32_bf16(a1, bk1, acck[nt], 0, 0, 0);
        accv[nt] = __builtin_amdgcn_mfma_f32_16x16x32_bf16(a0, bv0, accv[nt], 0, 0, 0);
        accv[nt] = __builtin_amdgcn_mfma_f32_16x16x32_bf16(a1, bv1, accv[nt], 0, 0, 0);
    }
    // stats for epilogue rows h*4+r live in lane (h*4+r)
    float mr[4], ir[4];
#pragma unroll
    for (int r = 0; r < 4; ++r) {
        int rl = h * 4 + r;
        mr[r] = __shfl(m, rl);
        ir[r] = __shfl(inv, rl);
    }
#pragma unroll
    for (int nt = 0; nt < 4; ++nt) {
        int j = nt * 16 + rloc;
        float cgkj = cgk[j], cbkj = cbk[j], cgvj = cgv[j], cbvj = cbv[j];
#pragma unroll
        for (int r = 0; r < 4; ++r) {
            long gro = (brow + h * 4 + r) * 64 + j;
            kout[gro] = f2bf(ir[r] * (acck[nt][r] - mr[r] * cgkj) + cbkj);
            vout[gro] = f2bf(ir[r] * (accv[nt][r] - mr[r] * cgvj) + cbvj);
        }
    }
}

// ---------------- slots_pre (iter 0 only): q = LN(slots)@Wq*scale, zero U,Z ----------------
__global__ __launch_bounds__(64) void slots_pre_kernel(
        const float* __restrict__ slots, const float* __restrict__ Wq,
        const float* __restrict__ lg, const float* __restrict__ lb,
        float* __restrict__ q, float* __restrict__ U, float* __restrict__ Z) {
    __shared__ float sn[64];
    int bs = blockIdx.x, d = threadIdx.x;
    float xv = slots[bs * 64 + d];
    float s1 = xv, s2 = xv * xv;
#pragma unroll
    for (int off = 1; off < 64; off <<= 1) {
        s1 += __shfl_xor(s1, off);
        s2 += __shfl_xor(s2, off);
    }
    float m = s1 * (1.f / 64.f);
    float var = s2 * (1.f / 64.f) - m * m;
    float inv = rsqrtf(var + LN_EPS);
    sn[d] = (xv - m) * inv * lg[d] + lb[d];
    __syncthreads();
    float acc = 0.f;
#pragma unroll 4
    for (int i = 0; i < 64; ++i) acc += sn[i] * Wq[i * 64 + d];
    q[bs * 64 + d] = acc * 0.125f;
    U[bs * 64 + d] = 0.f;
    if (d == 0) Z[bs] = 0.f;
}

// ---------------- attn: streaming pass, k in regs, v in LDS ----------------
__global__ __launch_bounds__(256) void attn_kernel(
        const unsigned short* __restrict__ kp, const unsigned short* __restrict__ vp,
        const float* __restrict__ q, float* __restrict__ U, float* __restrict__ Z) {
    __shared__ float smem[5120];
    float* vt = smem;            // [64][65]
    float* qs = smem + 4160;     // [7][64]
    float* al = smem + 4608;     // [64][8]
    int t = threadIdx.x;
    int b = blockIdx.x >> 4, blk = blockIdx.x & 15;
    int lane = t & 63, w = t >> 6;
    int row = t >> 2, p = t & 3;
    for (int i = t; i < NS * 64; i += 256) qs[i] = q[b * NS * 64 + i];
    float uacc[NS], zacc[NS];
#pragma unroll
    for (int s = 0; s < NS; ++s) { uacc[s] = 0.f; zacc[s] = 0.f; }
    __syncthreads();
    for (int c = 0; c < 4; ++c) {
        long base = ((long)b * NN + (blk * 4 + c) * 64) * 64 + t * 16;
        uint4 k0 = *(const uint4*)(kp + base);
        uint4 k1 = *(const uint4*)(kp + base + 8);
        uint4 v0 = *(const uint4*)(vp + base);
        uint4 v1 = *(const uint4*)(vp + base + 8);
        float kr[16], vr[16];
        unpack8(k0, kr); unpack8(k1, kr + 8);
        unpack8(v0, vr); unpack8(v1, vr + 8);
        float* vrow = vt + row * 65 + p * 16;
#pragma unroll
        for (int i = 0; i < 16; ++i) vrow[i] = vr[i];
        // phase 1: logits for this thread's row (quarter p)
        float lgt[NS];
#pragma unroll
        for (int s = 0; s < NS; ++s) {
            const float* qrow = qs + s * 64 + p * 16;
            float acc = 0.f;
#pragma unroll
            for (int i = 0; i < 16; i += 2) {
                float2 qv = *(const float2*)(qrow + i);
                acc += kr[i] * qv.x + kr[i + 1] * qv.y;
            }
            lgt[s] = acc;
        }
#pragma unroll
        for (int s = 0; s < NS; ++s) {
            lgt[s] += __shfl_xor(lgt[s], 1);
            lgt[s] += __shfl_xor(lgt[s], 2);
        }
        float mx = lgt[0];
#pragma unroll
        for (int s = 1; s < NS; ++s) mx = fmaxf(mx, lgt[s]);
        float se = 0.f, av[NS];
#pragma unroll
        for (int s = 0; s < NS; ++s) { av[s] = __expf(lgt[s] - mx); se += av[s]; }
        float rcp = 1.f / se;
#pragma unroll
        for (int s = 0; s < NS; ++s) av[s] = av[s] * rcp + EPS_ATTN;
        if (p == 0) {
            float4 st0 = {av[0], av[1], av[2], av[3]};
            float4 st1 = {av[4], av[5], av[6], 0.f};
            *(float4*)(al + row * 8) = st0;
            *(float4*)(al + row * 8 + 4) = st1;
        }
        // Z: butterfly over lane bits 2..5 sums the wave's 16 rows exactly once
#pragma unroll
        for (int s = 0; s < NS; ++s) {
            float zs = av[s];
            zs += __shfl_xor(zs, 4);  zs += __shfl_xor(zs, 8);
            zs += __shfl_xor(zs, 16); zs += __shfl_xor(zs, 32);
            zacc[s] += zs;
        }
        // phase 2: all LDS producers are this same wave -> no barrier needed
#pragma unroll
        for (int n = 0; n < 16; ++n) {
            int rr = w * 16 + n;
            float4 a03 = *(const float4*)(al + rr * 8);
            float4 a47 = *(const float4*)(al + rr * 8 + 4);
            float vv = vt[rr * 65 + lane];
            uacc[0] += a03.x * vv; uacc[1] += a03.y * vv;
            uacc[2] += a03.z * vv; uacc[3] += a03.w * vv;
            uacc[4] += a47.x * vv; uacc[5] += a47.y * vv;
            uacc[6] += a47.z * vv;
        }
    }
    __syncthreads();   // before reusing vt region for reduction
#pragma unroll
    for (int s = 0; s < NS; ++s) smem[(w * NS + s) * 64 + lane] = uacc[s];
    if (lane == 0) {
#pragma unroll
        for (int s = 0; s < NS; ++s) smem[1792 + w * NS + s] = zacc[s];
    }
    __syncthreads();
    for (int idx = t; idx < NS * 64; idx += 256) {
        float tot = smem[idx] + smem[448 + idx] + smem[896 + idx] + smem[1344 + idx];
        atomicAdd(&U[b * NS * 64 + idx], tot);
    }
    if (t < NS) {
        float tot = smem[1792 + t] + smem[1799 + t] + smem[1806 + t] + smem[1813 + t];
        atomicAdd(&Z[b * NS + t], tot);
    }
}

// ---------------- slots_post: updates=U/Z, GRU, LN, MLP, + next-iter q, zero U/Z ----------------
__global__ __launch_bounds__(256) void slots_post_kernel(
        float* __restrict__ slots, float* __restrict__ U, float* __restrict__ Z,
        const float* __restrict__ gW, const float* __restrict__ gU, const float* __restrict__ gb,
        const float* __restrict__ lmg, const float* __restrict__ lmb,
        const float* __restrict__ W1, const float* __restrict__ b1,
        const float* __restrict__ W2, const float* __restrict__ b2,
        const float* __restrict__ Wq, const float* __restrict__ lsg, const float* __restrict__ lsb,
        float* __restrict__ q, float* __restrict__ outp, int last) {
    __shared__ float up[64], hp[64], mx[192], mh[192], mm[64], hl[128], sn[64];
    int bs = blockIdx.x, t = threadIdx.x;
    if (t < 64) {
        float zsum = Z[bs];
        up[t] = U[bs * 64 + t] / zsum;
        hp[t] = slots[bs * 64 + t];
        U[bs * 64 + t] = 0.f;
        if (t == 0) Z[bs] = 0.f;
    }
    __syncthreads();
    if (t < 192) {
        float xa = gb[t], ha = gb[192 + t];
#pragma unroll 4
        for (int i = 0; i < 64; ++i) {
            xa += up[i] * gW[i * 192 + t];
            ha += hp[i] * gU[i * 192 + t];
        }
        mx[t] = xa; mh[t] = ha;
    }
    __syncthreads();
    float hnew = 0.f;
    if (t < 64) {
        float z = 1.f / (1.f + __expf(-(mx[t] + mh[t])));
        float r = 1.f / (1.f + __expf(-(mx[64 + t] + mh[64 + t])));
        float pre = mx[128 + t] + r * mh[128 + t];
        pre = fminf(fmaxf(pre, -15.f), 15.f);
        float e2 = __expf(2.f * pre);
        float hc = (e2 - 1.f) / (e2 + 1.f);
        hnew = z * hp[t] + (1.f - z) * hc;
        float s1 = hnew, s2 = hnew * hnew;
#pragma unroll
        for (int off = 1; off < 64; off <<= 1) { s1 += __shfl_xor(s1, off); s2 += __shfl_xor(s2, off); }
        float m = s1 * (1.f / 64.f);
        float var = s2 * (1.f / 64.f) - m * m;
        float inv = rsqrtf(var + LN_EPS);
        mm[t] = (hnew - m) * inv * lmg[t] + lmb[t];
    }
    __syncthreads();
    if (t < 128) {
        float h1 = b1[t];
#pragma unroll 4
        for (int i = 0; i < 64; ++i) h1 += mm[i] * W1[i * 128 + t];
        hl[t] = fmaxf(h1, 0.f);
    }
    __syncthreads();
    if (t < 64) {
        float o = hnew + b2[t];
#pragma unroll 4
        for (int j = 0; j < 128; ++j) o += hl[j] * W2[j * 64 + t];
        slots[bs * 64 + t] = o;
        if (last) outp[bs * 64 + t] = o;
        // LN_s + q for next iteration
        float s1 = o, s2 = o * o;
#pragma unroll
        for (int off = 1; off < 64; off <<= 1) { s1 += __shfl_xor(s1, off); s2 += __shfl_xor(s2, off); }
        float m = s1 * (1.f / 64.f);
        float var = s2 * (1.f / 64.f) - m * m;
        float inv = rsqrtf(var + LN_EPS);
        sn[t] = (o - m) * inv * lsg[t] + lsb[t];
    }
    __syncthreads();
    if (t < 64) {
        float acc = 0.f;
#pragma unroll 4
        for (int i = 0; i < 64; ++i) acc += sn[i] * Wq[i * 64 + t];
        q[bs * 64 + t] = acc * 0.125f;
    }
}

extern "C" void kernel_launch(void* const* d_in, const int* in_sizes, int n_in,
                              void* d_out, int out_size, void* d_ws, size_t ws_size,
                              hipStream_t stream) {
    const float* inputs  = (const float*)d_in[0];
    const float* noise   = (const float*)d_in[1];
    const float* ln_in_g = (const float*)d_in[2];
    const float* ln_in_b = (const float*)d_in[3];
    const float* ln_s_g  = (const float*)d_in[4];
    const float* ln_s_b  = (const float*)d_in[5];
    const float* ln_m_g  = (const float*)d_in[6];
    const float* ln_m_b  = (const float*)d_in[7];
    const float* Wq      = (const float*)d_in[8];
    const float* Wk      = (const float*)d_in[9];
    const float* Wv      = (const float*)d_in[10];
    const float* mu      = (const float*)d_in[11];
    const float* lsig    = (const float*)d_in[12];
    const float* gW      = (const float*)d_in[13];
    const float* gU      = (const float*)d_in[14];
    const float* gb      = (const float*)d_in[15];
    const float* W1      = (const float*)d_in[16];
    const float* b1      = (const float*)d_in[17];
    const float* W2      = (const float*)d_in[18];
    const float* b2      = (const float*)d_in[19];

    char* ws = (char*)d_ws;
    unsigned short* kbuf = (unsigned short*)ws;                        // 32MB
    unsigned short* vbuf = (unsigned short*)(ws + 33554432);           // 32MB
    float* slots = (float*)(ws + 67108864);
    float* qbuf  = (float*)(ws + 67108864 + 114688);
    float* Ubuf  = (float*)(ws + 67108864 + 2 * 114688);
    float* Zbuf  = (float*)(ws + 67108864 + 3 * 114688);
    unsigned short* GkT = (unsigned short*)(ws + 67108864 + 3 * 114688 + 4096);
    unsigned short* GvT = GkT + 4096;
    float* cgk = (float*)(GvT + 4096);
    float* cbk = cgk + 64;
    float* cgv = cbk + 64;
    float* cbv = cgv + 64;

    prep_kernel<<<128, 64, 0, stream>>>(Wk, Wv, ln_in_g, ln_in_b, GkT, GvT, cgk, cbk, cgv, cbv);
    init_slots_kernel<<<112, 256, 0, stream>>>(noise, mu, lsig, slots);
    proj_kernel<<<4096, 256, 0, stream>>>(inputs, GkT, GvT, cgk, cbk, cgv, cbv, kbuf, vbuf);
    slots_pre_kernel<<<448, 64, 0, stream>>>(slots, Wq, ln_s_g, ln_s_b, qbuf, Ubuf, Zbuf);
    for (int it = 0; it < 3; ++it) {
        attn_kernel<<<1024, 256, 0, stream>>>(kbuf, vbuf, qbuf, Ubuf, Zbuf);
        slots_post_kernel<<<448, 256, 0, stream>>>(slots, Ubuf, Zbuf, gW, gU, gb,
                                                   ln_m_g, ln_m_b, W1, b1, W2, b2,
                                                   Wq, ln_s_g, ln_s_b, qbuf,
                                                   (float*)d_out, (it == 2) ? 1 : 0);
    }
}

// Round 3
// 256.518 us; speedup vs baseline: 1.2950x; 1.2950x over previous
//
#include <hip/hip_runtime.h>
#include <hip/hip_bf16.h>

// SlotAttention on MI355X. B=64, N=4096, Din=D=64, S=7, H=128, 3 iters.
// v3: attn via MFMA (logits + PV), proj ILP-2 + vT output, post unrolled.

#define NB 64
#define NN 4096
#define NS 7
#define LN_EPS 1e-3f
#define EPS_ATTN 1e-8f

typedef __attribute__((ext_vector_type(8))) __bf16 bf16x8;
typedef __attribute__((ext_vector_type(8))) unsigned short u16x8;
typedef __attribute__((ext_vector_type(4))) float f32x4;
typedef __attribute__((ext_vector_type(4))) unsigned int u32x4;

__device__ __forceinline__ unsigned short f2bf(float f) {
    unsigned int x = __float_as_uint(f);
    x += 0x7FFFu + ((x >> 16) & 1u);
    return (unsigned short)(x >> 16);
}

__device__ __forceinline__ bf16x8 pack8(float4 a, float4 b) {
    u16x8 r;
    r[0] = f2bf(a.x); r[1] = f2bf(a.y); r[2] = f2bf(a.z); r[3] = f2bf(a.w);
    r[4] = f2bf(b.x); r[5] = f2bf(b.y); r[6] = f2bf(b.z); r[7] = f2bf(b.w);
    return __builtin_bit_cast(bf16x8, r);
}

// ---------------- prep: G^T = (g (.) W)^T bf16, colsums ----------------
__global__ __launch_bounds__(64) void prep_kernel(
        const float* __restrict__ Wk, const float* __restrict__ Wv,
        const float* __restrict__ g, const float* __restrict__ bb,
        unsigned short* __restrict__ GkT, unsigned short* __restrict__ GvT,
        float* __restrict__ cgk, float* __restrict__ cbk,
        float* __restrict__ cgv, float* __restrict__ cbv) {
    int j = blockIdx.x & 63, mat = blockIdx.x >> 6, d = threadIdx.x;
    const float* W = mat ? Wv : Wk;
    unsigned short* GT = mat ? GvT : GkT;
    float* cg = mat ? cgv : cgk;
    float* cb = mat ? cbv : cbk;
    float w = W[d * 64 + j];
    float gv = g[d], bv = bb[d];
    GT[j * 64 + d] = f2bf(gv * w);
    float sg = gv * w, sb = bv * w;
#pragma unroll
    for (int off = 1; off < 64; off <<= 1) {
        sg += __shfl_xor(sg, off);
        sb += __shfl_xor(sb, off);
    }
    if (d == 0) { cg[j] = sg; cb[j] = sb; }
}

// ---------------- init slots ----------------
__global__ void init_slots_kernel(const float* __restrict__ noise, const float* __restrict__ mu,
                                  const float* __restrict__ lsig, float* __restrict__ slots) {
    int idx = blockIdx.x * 256 + threadIdx.x;
    if (idx < NB * NS * 64) {
        int d = idx & 63;
        slots[idx] = mu[d] + __expf(lsig[d]) * noise[idx];
    }
}

// ---------------- proj: k (row-major), vT (d-major) = LN(x)@W, MFMA, ILP-2 ----------------
__global__ __launch_bounds__(256) void proj_kernel(
        const float* __restrict__ x, const unsigned short* __restrict__ GkT,
        const unsigned short* __restrict__ GvT,
        const float* __restrict__ cgk, const float* __restrict__ cbk,
        const float* __restrict__ cgv, const float* __restrict__ cbv,
        unsigned short* __restrict__ kout, unsigned short* __restrict__ vT) {
    int t = threadIdx.x;
    int w = t >> 6, lane = t & 63;
    int h = lane >> 4, rl = lane & 15;
    long base = (long)blockIdx.x * 128;         // global row base (block = 128 rows)
    int bb = blockIdx.x >> 5;                   // batch (32 blocks/batch)
    int nblk = (blockIdx.x & 31) * 128;         // n offset within batch
    const float* xr0 = x + (base + w * 16 + rl) * 64 + h * 8;
    const float* xr1 = xr0 + 64 * 64;
    float4 xa[8];
    xa[0] = *(const float4*)(xr0);      xa[1] = *(const float4*)(xr0 + 4);
    xa[2] = *(const float4*)(xr0 + 32); xa[3] = *(const float4*)(xr0 + 36);
    xa[4] = *(const float4*)(xr1);      xa[5] = *(const float4*)(xr1 + 4);
    xa[6] = *(const float4*)(xr1 + 32); xa[7] = *(const float4*)(xr1 + 36);
    float s1a = 0.f, s2a = 0.f, s1b = 0.f, s2b = 0.f;
#pragma unroll
    for (int i = 0; i < 4; ++i) {
        s1a += xa[i].x + xa[i].y + xa[i].z + xa[i].w;
        s2a += xa[i].x * xa[i].x + xa[i].y * xa[i].y + xa[i].z * xa[i].z + xa[i].w * xa[i].w;
        s1b += xa[4 + i].x + xa[4 + i].y + xa[4 + i].z + xa[4 + i].w;
        s2b += xa[4 + i].x * xa[4 + i].x + xa[4 + i].y * xa[4 + i].y + xa[4 + i].z * xa[4 + i].z + xa[4 + i].w * xa[4 + i].w;
    }
    s1a += __shfl_xor(s1a, 16); s2a += __shfl_xor(s2a, 16);
    s1a += __shfl_xor(s1a, 32); s2a += __shfl_xor(s2a, 32);
    s1b += __shfl_xor(s1b, 16); s2b += __shfl_xor(s2b, 16);
    s1b += __shfl_xor(s1b, 32); s2b += __shfl_xor(s2b, 32);
    float m0 = s1a * (1.f / 64.f);
    float i0 = rsqrtf(s2a * (1.f / 64.f) - m0 * m0 + LN_EPS);
    float m1 = s1b * (1.f / 64.f);
    float i1 = rsqrtf(s2b * (1.f / 64.f) - m1 * m1 + LN_EPS);
    bf16x8 a00 = pack8(xa[0], xa[1]), a01 = pack8(xa[2], xa[3]);
    bf16x8 a10 = pack8(xa[4], xa[5]), a11 = pack8(xa[6], xa[7]);
    f32x4 k0a[4], v0a[4], k1a[4], v1a[4];
#pragma unroll
    for (int nt = 0; nt < 4; ++nt) {
        k0a[nt] = (f32x4){0.f, 0.f, 0.f, 0.f}; v0a[nt] = (f32x4){0.f, 0.f, 0.f, 0.f};
        k1a[nt] = (f32x4){0.f, 0.f, 0.f, 0.f}; v1a[nt] = (f32x4){0.f, 0.f, 0.f, 0.f};
    }
#pragma unroll
    for (int nt = 0; nt < 4; ++nt) {
        const unsigned short* gk = GkT + (nt * 16 + rl) * 64 + h * 8;
        const unsigned short* gv = GvT + (nt * 16 + rl) * 64 + h * 8;
        bf16x8 bk0 = *(const bf16x8*)(gk);
        bf16x8 bk1 = *(const bf16x8*)(gk + 32);
        bf16x8 bv0 = *(const bf16x8*)(gv);
        bf16x8 bv1 = *(const bf16x8*)(gv + 32);
        k0a[nt] = __builtin_amdgcn_mfma_f32_16x16x32_bf16(a00, bk0, k0a[nt], 0, 0, 0);
        k0a[nt] = __builtin_amdgcn_mfma_f32_16x16x32_bf16(a01, bk1, k0a[nt], 0, 0, 0);
        v0a[nt] = __builtin_amdgcn_mfma_f32_16x16x32_bf16(a00, bv0, v0a[nt], 0, 0, 0);
        v0a[nt] = __builtin_amdgcn_mfma_f32_16x16x32_bf16(a01, bv1, v0a[nt], 0, 0, 0);
        k1a[nt] = __builtin_amdgcn_mfma_f32_16x16x32_bf16(a10, bk0, k1a[nt], 0, 0, 0);
        k1a[nt] = __builtin_amdgcn_mfma_f32_16x16x32_bf16(a11, bk1, k1a[nt], 0, 0, 0);
        v1a[nt] = __builtin_amdgcn_mfma_f32_16x16x32_bf16(a10, bv0, v1a[nt], 0, 0, 0);
        v1a[nt] = __builtin_amdgcn_mfma_f32_16x16x32_bf16(a11, bv1, v1a[nt], 0, 0, 0);
    }
    float mr0[4], ir0[4], mr1[4], ir1[4];
#pragma unroll
    for (int r = 0; r < 4; ++r) {
        int rlsrc = h * 4 + r;
        mr0[r] = __shfl(m0, rlsrc); ir0[r] = __shfl(i0, rlsrc);
        mr1[r] = __shfl(m1, rlsrc); ir1[r] = __shfl(i1, rlsrc);
    }
#pragma unroll
    for (int nt = 0; nt < 4; ++nt) {
        int j = nt * 16 + rl;
        float cgkj = cgk[j], cbkj = cbk[j], cgvj = cgv[j], cbvj = cbv[j];
        // tile 0
        unsigned int vp0 = 0, vp1 = 0;
#pragma unroll
        for (int r = 0; r < 4; ++r) {
            long row = base + w * 16 + h * 4 + r;
            kout[row * 64 + j] = f2bf(ir0[r] * (k0a[nt][r] - mr0[r] * cgkj) + cbkj);
            unsigned int vb = f2bf(ir0[r] * (v0a[nt][r] - mr0[r] * cgvj) + cbvj);
            if (r < 2) vp0 |= vb << (16 * r); else vp1 |= vb << (16 * (r - 2));
        }
        {
            long vaddr = ((long)(bb * 64 + j)) * NN + nblk + w * 16 + h * 4;
            *(uint2*)(vT + vaddr) = make_uint2(vp0, vp1);
        }
        // tile 1
        vp0 = 0; vp1 = 0;
#pragma unroll
        for (int r = 0; r < 4; ++r) {
            long row = base + 64 + w * 16 + h * 4 + r;
            kout[row * 64 + j] = f2bf(ir1[r] * (k1a[nt][r] - mr1[r] * cgkj) + cbkj);
            unsigned int vb = f2bf(ir1[r] * (v1a[nt][r] - mr1[r] * cgvj) + cbvj);
            if (r < 2) vp0 |= vb << (16 * r); else vp1 |= vb << (16 * (r - 2));
        }
        {
            long vaddr = ((long)(bb * 64 + j)) * NN + nblk + 64 + w * 16 + h * 4;
            *(uint2*)(vT + vaddr) = make_uint2(vp0, vp1);
        }
    }
}

// ---------------- slots_pre (iter 0): q = LN(slots)@Wq*scale, zero U,Z ----------------
__global__ __launch_bounds__(64) void slots_pre_kernel(
        const float* __restrict__ slots, const float* __restrict__ Wq,
        const float* __restrict__ lg, const float* __restrict__ lb,
        float* __restrict__ q, float* __restrict__ U, float* __restrict__ Z) {
    __shared__ float sn[64];
    int bs = blockIdx.x, d = threadIdx.x;
    float xv = slots[bs * 64 + d];
    float s1 = xv, s2 = xv * xv;
#pragma unroll
    for (int off = 1; off < 64; off <<= 1) {
        s1 += __shfl_xor(s1, off);
        s2 += __shfl_xor(s2, off);
    }
    float m = s1 * (1.f / 64.f);
    float inv = rsqrtf(s2 * (1.f / 64.f) - m * m + LN_EPS);
    sn[d] = (xv - m) * inv * lg[d] + lb[d];
    __syncthreads();
    float acc = 0.f;
#pragma unroll 8
    for (int i = 0; i < 64; ++i) acc += sn[i] * Wq[i * 64 + d];
    q[bs * 64 + d] = acc * 0.125f;
    U[bs * 64 + d] = 0.f;
    if (d == 0) Z[bs] = 0.f;
}

// ---------------- attn: MFMA logits + MFMA PV ----------------
// block = 256 rows of one batch; wave handles 16 rows/step, 4 steps;
// PV over step-pairs (K=32). No barriers in the main loop.
__global__ __launch_bounds__(256) void attn_kernel(
        const unsigned short* __restrict__ kp, const unsigned short* __restrict__ vtp,
        const float* __restrict__ q, float* __restrict__ U, float* __restrict__ Z) {
    __shared__ unsigned int plds[4][320];   // per-wave P^T staging, [16 slots][20 u32-pairs]
    __shared__ float ured[4][512];
    int t = threadIdx.x;
    int b = blockIdx.x >> 4, blk = blockIdx.x & 15;
    int w = t >> 6, lane = t & 63;
    int h = lane >> 4, c = lane & 15;
    // q B-fragments (slot = c; zero for c >= 7)
    bf16x8 qf0, qf1;
    {
        int cs = (c < 7) ? c : 0;
        const float* qr = q + (b * NS + cs) * 64 + h * 8;
        float4 q0 = *(const float4*)(qr);
        float4 q1 = *(const float4*)(qr + 4);
        float4 q2 = *(const float4*)(qr + 32);
        float4 q3 = *(const float4*)(qr + 36);
        if (c >= 7) {
            q0 = make_float4(0.f, 0.f, 0.f, 0.f); q1 = q0; q2 = q0; q3 = q0;
        }
        qf0 = pack8(q0, q1);
        qf1 = pack8(q2, q3);
    }
    f32x4 pv[4];
#pragma unroll
    for (int i = 0; i < 4; ++i) pv[i] = (f32x4){0.f, 0.f, 0.f, 0.f};
    float zac = 0.f;
    unsigned int* pw = plds[w];
    long rb0 = (long)b * NN + blk * 256 + w * 16;
#pragma unroll
    for (int p = 0; p < 2; ++p) {
#pragma unroll
        for (int sh = 0; sh < 2; ++sh) {
            long rowbase = rb0 + p * 128 + sh * 64;
            const unsigned short* ka = kp + (rowbase + c) * 64 + h * 8;
            bf16x8 a0 = *(const bf16x8*)(ka);
            bf16x8 a1 = *(const bf16x8*)(ka + 32);
            f32x4 lg = (f32x4){0.f, 0.f, 0.f, 0.f};
            lg = __builtin_amdgcn_mfma_f32_16x16x32_bf16(a0, qf0, lg, 0, 0, 0);
            lg = __builtin_amdgcn_mfma_f32_16x16x32_bf16(a1, qf1, lg, 0, 0, 0);
            // softmax over slots (c-lanes) for each of 4 rows
            float av[4];
#pragma unroll
            for (int j = 0; j < 4; ++j) {
                float vl = (c < 7) ? lg[j] : -1e30f;
                float mx = vl;
                mx = fmaxf(mx, __shfl_xor(mx, 1));
                mx = fmaxf(mx, __shfl_xor(mx, 2));
                mx = fmaxf(mx, __shfl_xor(mx, 4));
                mx = fmaxf(mx, __shfl_xor(mx, 8));
                float e = (c < 7) ? __expf(lg[j] - mx) : 0.f;
                float se = e;
                se += __shfl_xor(se, 1);
                se += __shfl_xor(se, 2);
                se += __shfl_xor(se, 4);
                se += __shfl_xor(se, 8);
                float a = (c < 7) ? (__fdividef(e, se) + EPS_ATTN) : 0.f;
                av[j] = a;
                zac += a;
            }
            // stage P^T as bf16 pairs: pair idx = sh*8 + 2h + jj
            unsigned int w0 = (unsigned int)f2bf(av[0]) | ((unsigned int)f2bf(av[1]) << 16);
            unsigned int w1 = (unsigned int)f2bf(av[2]) | ((unsigned int)f2bf(av[3]) << 16);
            pw[c * 20 + sh * 8 + 2 * h]     = w0;
            pw[c * 20 + sh * 8 + 2 * h + 1] = w1;
        }
        // PV for this step-pair: A = P^T (rows=slots, K=32 local k-rows)
        u32x4 pr = *(u32x4*)(&pw[c * 20 + 4 * h]);
        bf16x8 pa = __builtin_bit_cast(bf16x8, pr);
        int nb = blk * 256 + p * 128 + ((h < 2) ? (w * 16 + 8 * h) : (48 + w * 16 + 8 * h));
#pragma unroll
        for (int tile = 0; tile < 4; ++tile) {
            const unsigned short* vb = vtp + ((long)(b * 64 + tile * 16 + c)) * NN + nb;
            bf16x8 bv = *(const bf16x8*)(vb);
            pv[tile] = __builtin_amdgcn_mfma_f32_16x16x32_bf16(pa, bv, pv[tile], 0, 0, 0);
        }
    }
    // Z: lane holds partial for slot c over this wave's rows; reduce over h
    zac += __shfl_xor(zac, 16);
    zac += __shfl_xor(zac, 32);
    if (h == 0 && c < 7) atomicAdd(Z + b * NS + c, zac);
    // U block-reduce: pv rows = slots (4h+j), cols = d (tile*16+c); valid h<2
    if (h < 2) {
#pragma unroll
        for (int tile = 0; tile < 4; ++tile) {
#pragma unroll
            for (int j = 0; j < 4; ++j) {
                ured[w][(4 * h + j) * 64 + tile * 16 + c] = pv[tile][j];
            }
        }
    }
    __syncthreads();
    for (int idx = t; idx < NS * 64; idx += 256) {
        float tot = ured[0][idx] + ured[1][idx] + ured[2][idx] + ured[3][idx];
        atomicAdd(U + b * NS * 64 + idx, tot);
    }
}

// ---------------- slots_post: updates=U/Z, GRU, LN, MLP, next-iter q, zero U/Z ----------------
__global__ __launch_bounds__(256) void slots_post_kernel(
        float* __restrict__ slots, float* __restrict__ U, float* __restrict__ Z,
        const float* __restrict__ gW, const float* __restrict__ gU, const float* __restrict__ gb,
        const float* __restrict__ lmg, const float* __restrict__ lmb,
        const float* __restrict__ W1, const float* __restrict__ b1,
        const float* __restrict__ W2, const float* __restrict__ b2,
        const float* __restrict__ Wq, const float* __restrict__ lsg, const float* __restrict__ lsb,
        float* __restrict__ q, float* __restrict__ outp, int last) {
    __shared__ float up[64], hp[64], mx[192], mh[192], mm[64], hl[128], sn[64];
    int bs = blockIdx.x, t = threadIdx.x;
    if (t < 64) {
        float zsum = Z[bs];
        up[t] = U[bs * 64 + t] / zsum;
        hp[t] = slots[bs * 64 + t];
        U[bs * 64 + t] = 0.f;
        if (t == 0) Z[bs] = 0.f;
    }
    __syncthreads();
    if (t < 192) {
        float xa0 = gb[t], ha0 = gb[192 + t], xa1 = 0.f, ha1 = 0.f;
#pragma unroll 8
        for (int i = 0; i < 64; i += 2) {
            xa0 += up[i] * gW[i * 192 + t];
            ha0 += hp[i] * gU[i * 192 + t];
            xa1 += up[i + 1] * gW[(i + 1) * 192 + t];
            ha1 += hp[i + 1] * gU[(i + 1) * 192 + t];
        }
        mx[t] = xa0 + xa1; mh[t] = ha0 + ha1;
    }
    __syncthreads();
    float hnew = 0.f;
    if (t < 64) {
        float z = 1.f / (1.f + __expf(-(mx[t] + mh[t])));
        float r = 1.f / (1.f + __expf(-(mx[64 + t] + mh[64 + t])));
        float pre = mx[128 + t] + r * mh[128 + t];
        pre = fminf(fmaxf(pre, -15.f), 15.f);
        float e2 = __expf(2.f * pre);
        float hc = (e2 - 1.f) / (e2 + 1.f);
        hnew = z * hp[t] + (1.f - z) * hc;
        float s1 = hnew, s2 = hnew * hnew;
#pragma unroll
        for (int off = 1; off < 64; off <<= 1) { s1 += __shfl_xor(s1, off); s2 += __shfl_xor(s2, off); }
        float m = s1 * (1.f / 64.f);
        float inv = rsqrtf(s2 * (1.f / 64.f) - m * m + LN_EPS);
        mm[t] = (hnew - m) * inv * lmg[t] + lmb[t];
    }
    __syncthreads();
    if (t < 128) {
        float h1 = b1[t], h2 = 0.f;
#pragma unroll 8
        for (int i = 0; i < 64; i += 2) {
            h1 += mm[i] * W1[i * 128 + t];
            h2 += mm[i + 1] * W1[(i + 1) * 128 + t];
        }
        hl[t] = fmaxf(h1 + h2, 0.f);
    }
    __syncthreads();
    if (t < 64) {
        float o = hnew + b2[t], o1 = 0.f;
#pragma unroll 8
        for (int j = 0; j < 128; j += 2) {
            o += hl[j] * W2[j * 64 + t];
            o1 += hl[j + 1] * W2[(j + 1) * 64 + t];
        }
        o += o1;
        slots[bs * 64 + t] = o;
        if (last) outp[bs * 64 + t] = o;
        float s1 = o, s2 = o * o;
#pragma unroll
        for (int off = 1; off < 64; off <<= 1) { s1 += __shfl_xor(s1, off); s2 += __shfl_xor(s2, off); }
        float m = s1 * (1.f / 64.f);
        float inv = rsqrtf(s2 * (1.f / 64.f) - m * m + LN_EPS);
        sn[t] = (o - m) * inv * lsg[t] + lsb[t];
    }
    __syncthreads();
    if (t < 64) {
        float acc = 0.f;
#pragma unroll 8
        for (int i = 0; i < 64; ++i) acc += sn[i] * Wq[i * 64 + t];
        q[bs * 64 + t] = acc * 0.125f;
    }
}

extern "C" void kernel_launch(void* const* d_in, const int* in_sizes, int n_in,
                              void* d_out, int out_size, void* d_ws, size_t ws_size,
                              hipStream_t stream) {
    const float* inputs  = (const float*)d_in[0];
    const float* noise   = (const float*)d_in[1];
    const float* ln_in_g = (const float*)d_in[2];
    const float* ln_in_b = (const float*)d_in[3];
    const float* ln_s_g  = (const float*)d_in[4];
    const float* ln_s_b  = (const float*)d_in[5];
    const float* ln_m_g  = (const float*)d_in[6];
    const float* ln_m_b  = (const float*)d_in[7];
    const float* Wq      = (const float*)d_in[8];
    const float* Wk      = (const float*)d_in[9];
    const float* Wv      = (const float*)d_in[10];
    const float* mu      = (const float*)d_in[11];
    const float* lsig    = (const float*)d_in[12];
    const float* gW      = (const float*)d_in[13];
    const float* gU      = (const float*)d_in[14];
    const float* gb      = (const float*)d_in[15];
    const float* W1      = (const float*)d_in[16];
    const float* b1      = (const float*)d_in[17];
    const float* W2      = (const float*)d_in[18];
    const float* b2      = (const float*)d_in[19];

    char* ws = (char*)d_ws;
    unsigned short* kbuf = (unsigned short*)ws;                        // 32MB, [b][n][64]
    unsigned short* vtbuf = (unsigned short*)(ws + 33554432);          // 32MB, [b][64][4096]
    float* slots = (float*)(ws + 67108864);
    float* qbuf  = (float*)(ws + 67108864 + 114688);
    float* Ubuf  = (float*)(ws + 67108864 + 2 * 114688);
    float* Zbuf  = (float*)(ws + 67108864 + 3 * 114688);
    unsigned short* GkT = (unsigned short*)(ws + 67108864 + 3 * 114688 + 4096);
    unsigned short* GvT = GkT + 4096;
    float* cgk = (float*)(GvT + 4096);
    float* cbk = cgk + 64;
    float* cgv = cbk + 64;
    float* cbv = cgv + 64;

    prep_kernel<<<128, 64, 0, stream>>>(Wk, Wv, ln_in_g, ln_in_b, GkT, GvT, cgk, cbk, cgv, cbv);
    init_slots_kernel<<<112, 256, 0, stream>>>(noise, mu, lsig, slots);
    proj_kernel<<<2048, 256, 0, stream>>>(inputs, GkT, GvT, cgk, cbk, cgv, cbv, kbuf, vtbuf);
    slots_pre_kernel<<<448, 64, 0, stream>>>(slots, Wq, ln_s_g, ln_s_b, qbuf, Ubuf, Zbuf);
    for (int it = 0; it < 3; ++it) {
        attn_kernel<<<1024, 256, 0, stream>>>(kbuf, vtbuf, qbuf, Ubuf, Zbuf);
        slots_post_kernel<<<448, 256, 0, stream>>>(slots, Ubuf, Zbuf, gW, gU, gb,
                                                   ln_m_g, ln_m_b, W1, b1, W2, b2,
                                                   Wq, ln_s_g, ln_s_b, qbuf,
                                                   (float*)d_out, (it == 2) ? 1 : 0);
    }
}